// Round 10
// baseline (353.540 us; speedup 1.0000x reference)
//
#include <hip/hip_runtime.h>
#include <hip/hip_bf16.h>
#include <math.h>

// GATv2 encoder, 11-node graph:
//   memset(deg) -> hist -> blocksum -> scanpartial(+zero pooledR/done) -> scanfinal
//   -> scatter -> fold1(+cat2) -> gemm1(mfma, f32 A) -> node_conv1
//   -> gemm2(mfma, bf16 A) -> node_conv2(+pool(64 replicas)+out, last-block ticket)
// Unnormalized-exp softmax (logits bounded); att pre-scaled by LOG2E -> exp2f.
// Convs: 2-stream software pipeline (ring-4 with per-iter branches regressed — R9).

#define NEG_SLOPE 0.2f
#define LOG2E 1.4426950408889634f
#define NREP 64

typedef __attribute__((ext_vector_type(8))) short bf16x8;
typedef __attribute__((ext_vector_type(4))) float f32x4;

__device__ __forceinline__ float leaky(float t) { return fmaxf(t, NEG_SLOPE * t); }
__device__ __forceinline__ float bf2f(unsigned short u) {
    return __uint_as_float((unsigned)u << 16);
}
__device__ __forceinline__ short f2bf(float f) {
    __hip_bfloat16 h = __float2bfloat16(f);
    return *reinterpret_cast<short*>(&h);
}

// ---------------- CSR build ----------------
__global__ void hist_kernel(const int* __restrict__ ei, int* __restrict__ deg,
                            int E, int Etot) {
    int e = blockIdx.x * blockDim.x + threadIdx.x;
    if (e >= Etot) return;
    int d = (e < E) ? ei[E + e] : (e - E);
    atomicAdd(&deg[d], 1);
}

__global__ __launch_bounds__(256) void blocksum_kernel(const int* __restrict__ deg,
                                                       int* __restrict__ partial, int N) {
    __shared__ int sh[256];
    int i = blockIdx.x * 256 + threadIdx.x;
    sh[threadIdx.x] = (i < N) ? deg[i] : 0;
    __syncthreads();
    for (int off = 128; off > 0; off >>= 1) {
        if (threadIdx.x < off) sh[threadIdx.x] += sh[threadIdx.x + off];
        __syncthreads();
    }
    if (threadIdx.x == 0) partial[blockIdx.x] = sh[0];
}

__global__ __launch_bounds__(256) void scanpartial_kernel(int* partial, int nb,
                                                          int* rowstart, int* done_ctr,
                                                          float* pooledR,
                                                          int N, int Etot) {
    __shared__ int sh[256];
    int t = threadIdx.x;
    for (int i = t; i < NREP * 32; i += 256) pooledR[i] = 0.f;
    int v = (t < nb) ? partial[t] : 0;
    sh[t] = v;
    __syncthreads();
    for (int off = 1; off < 256; off <<= 1) {
        int u = (t >= off) ? sh[t - off] : 0;
        __syncthreads();
        sh[t] += u;
        __syncthreads();
    }
    if (t < nb) partial[t] = sh[t] - v;
    if (t == 0) { rowstart[N] = Etot; *done_ctr = 0; }
}

__global__ __launch_bounds__(256) void scanfinal_kernel(const int* __restrict__ deg,
                                                        const int* __restrict__ partial,
                                                        int* __restrict__ rowstart,
                                                        int* __restrict__ cursor, int N) {
    __shared__ int sh[256];
    int i = blockIdx.x * 256 + threadIdx.x;
    int v = (i < N) ? deg[i] : 0;
    sh[threadIdx.x] = v;
    __syncthreads();
    for (int off = 1; off < 256; off <<= 1) {
        int t = (threadIdx.x >= off) ? sh[threadIdx.x - off] : 0;
        __syncthreads();
        sh[threadIdx.x] += t;
        __syncthreads();
    }
    if (i < N) {
        int ex = partial[blockIdx.x] + sh[threadIdx.x] - v;
        rowstart[i] = ex;
        cursor[i] = ex;
    }
}

__global__ void scatter_kernel(const int* __restrict__ ei, int* __restrict__ cursor,
                               int* __restrict__ csr_src, int E, int Etot) {
    int e = blockIdx.x * blockDim.x + threadIdx.x;
    if (e >= Etot) return;
    int s, d;
    if (e < E) { s = ei[e]; d = ei[E + e]; } else { s = d = e - E; }
    int pos = atomicAdd(&cursor[d], 1);
    csr_src[pos] = s;
}

// ---------------- weight prep: fold1 (b<256) + cat2 (b>=256) ----------------
__global__ __launch_bounds__(128) void fold1_kernel(const float* __restrict__ Win,
                                                    const float* __restrict__ b_in,
                                                    const float* __restrict__ Wl1,
                                                    const float* __restrict__ bl1,
                                                    const float* __restrict__ Wr1,
                                                    const float* __restrict__ br1,
                                                    const float* __restrict__ Wl2,
                                                    const float* __restrict__ bl2,
                                                    const float* __restrict__ Wr2,
                                                    const float* __restrict__ br2,
                                                    unsigned short* __restrict__ Wcat1,
                                                    float* __restrict__ bcat1,
                                                    unsigned short* __restrict__ Wcat2,
                                                    float* __restrict__ bcat2) {
    int b = blockIdx.x;
    int k = threadIdx.x;  // 0..127
    if (b >= 256) {
        int fb = b - 256;  // 0..31
        for (int i = fb * 128 + k; i < 64 * 128; i += 32 * 128) {
            int m = i >> 7, kk = i & 127;
            float v = (m < 32) ? Wl2[m * 128 + kk] : Wr2[(m - 32) * 128 + kk];
            Wcat2[i] = (unsigned short)f2bf(v);
        }
        if (fb == 0 && k < 64) bcat2[k] = (k < 32) ? bl2[k] : br2[k - 32];
        return;
    }
    int o = b;            // 0..255
    const float* Wx = (o < 128) ? Wl1 : Wr1;
    const float* bx = (o < 128) ? bl1 : br1;
    int oo = o & 127;
    float acc = 0.f;
#pragma unroll 16
    for (int j = 0; j < 128; ++j)
        acc = fmaf(Wx[oo * 128 + j], Win[j * 128 + k], acc);
    Wcat1[o * 128 + k] = (unsigned short)f2bf(acc);

    __shared__ float red[128];
    red[k] = Wx[oo * 128 + k] * b_in[k];
    __syncthreads();
    for (int off = 64; off > 0; off >>= 1) {
        if (k < off) red[k] += red[k + off];
        __syncthreads();
    }
    if (k == 0) bcat1[o] = red[0] + bx[oo];
}

// ---------------- MFMA GEMM ----------------
template <int CT, int S, bool A_F32>
__global__ __launch_bounds__(256) void gemm_mfma(const void* __restrict__ Av,
                                                 const unsigned short* __restrict__ W,
                                                 const float* __restrict__ bias,
                                                 unsigned short* __restrict__ OUT0,
                                                 unsigned short* __restrict__ OUT1,
                                                 int N) {
    const int w = threadIdx.x >> 6;
    const int lane = threadIdx.x & 63;
    const int ln = lane & 15;
    const int quad = lane >> 4;
    const int nb = blockIdx.x * 64;
    const int c0 = w * CT * 16;

    f32x4 acc[4][CT];
#pragma unroll
    for (int rt = 0; rt < 4; ++rt)
#pragma unroll
        for (int ct = 0; ct < CT; ++ct) acc[rt][ct] = (f32x4){0.f, 0.f, 0.f, 0.f};

    int rows[4];
#pragma unroll
    for (int rt = 0; rt < 4; ++rt) {
        int n = nb + rt * 16 + ln;
        rows[rt] = n < N ? n : N - 1;
    }

#pragma unroll
    for (int kc = 0; kc < 4; ++kc) {
        const int k0 = kc * 32 + quad * 8;
        bf16x8 a[4], wv[CT];
#pragma unroll
        for (int rt = 0; rt < 4; ++rt) {
            if (A_F32) {
                const float* p = (const float*)Av + (size_t)rows[rt] * 128 + k0;
                float4 u = *(const float4*)p;
                float4 v = *(const float4*)(p + 4);
                a[rt][0] = f2bf(u.x); a[rt][1] = f2bf(u.y);
                a[rt][2] = f2bf(u.z); a[rt][3] = f2bf(u.w);
                a[rt][4] = f2bf(v.x); a[rt][5] = f2bf(v.y);
                a[rt][6] = f2bf(v.z); a[rt][7] = f2bf(v.w);
            } else {
                a[rt] = *(const bf16x8*)((const unsigned short*)Av + (size_t)rows[rt] * 128 + k0);
            }
        }
#pragma unroll
        for (int ct = 0; ct < CT; ++ct)
            wv[ct] = *(const bf16x8*)(W + (size_t)(c0 + ct * 16 + ln) * 128 + k0);
#pragma unroll
        for (int rt = 0; rt < 4; ++rt)
#pragma unroll
            for (int ct = 0; ct < CT; ++ct)
                acc[rt][ct] = __builtin_amdgcn_mfma_f32_16x16x32_bf16(wv[ct], a[rt], acc[rt][ct], 0, 0, 0);
    }

#pragma unroll
    for (int rt = 0; rt < 4; ++rt) {
        int n = nb + rt * 16 + ln;
        if (n >= N) continue;
#pragma unroll
        for (int ct = 0; ct < CT; ++ct) {
            int cb = c0 + ct * 16 + quad * 4;
            float4 bv = *(const float4*)&bias[cb];
            ushort4 o;
            o.x = (unsigned short)f2bf(acc[rt][ct][0] + bv.x);
            o.y = (unsigned short)f2bf(acc[rt][ct][1] + bv.y);
            o.z = (unsigned short)f2bf(acc[rt][ct][2] + bv.z);
            o.w = (unsigned short)f2bf(acc[rt][ct][3] + bv.w);
            if (cb < S) *(ushort4*)&OUT0[(size_t)n * S + cb] = o;
            else        *(ushort4*)&OUT1[(size_t)n * S + cb - S] = o;
        }
    }
}

// ================= conv1 fused: 32 lanes/node, 2 edge streams =================
__global__ __launch_bounds__(256) void node_conv1(const unsigned short* __restrict__ XL,
                                                  const unsigned short* __restrict__ XR,
                                                  const int* __restrict__ rowstart,
                                                  const int* __restrict__ csr_src,
                                                  const float* __restrict__ att,
                                                  const float* __restrict__ bias,
                                                  unsigned short* __restrict__ H1, int N) {
    int d = blockIdx.x * 8 + (threadIdx.x >> 5);
    if (d >= N) return;
    int l = threadIdx.x & 31;
    int c0 = 4 * l;
    int rs = rowstart[d], re = rowstart[d + 1];

    float4 attv = *(const float4*)&att[c0];
    attv.x *= LOG2E; attv.y *= LOG2E; attv.z *= LOG2E; attv.w *= LOG2E;
    ushort4 xru = *(const ushort4*)&XR[(size_t)d * 128 + c0];
    float xr0 = bf2f(xru.x), xr1 = bf2f(xru.y), xr2 = bf2f(xru.z), xr3 = bf2f(xru.w);

    float sA = 0.f, aA0 = 0.f, aA1 = 0.f, aA2 = 0.f, aA3 = 0.f;
    float sB = 0.f, aB0 = 0.f, aB1 = 0.f, aB2 = 0.f, aB3 = 0.f;

#define PROC1(xu, SS, A0, A1, A2, A3)                                      \
    {                                                                      \
        float x0 = bf2f(xu.x), x1 = bf2f(xu.y), x2 = bf2f(xu.z), x3 = bf2f(xu.w); \
        float p = leaky(x0 + xr0) * attv.x;                                \
        p = fmaf(leaky(x1 + xr1), attv.y, p);                              \
        p = fmaf(leaky(x2 + xr2), attv.z, p);                              \
        p = fmaf(leaky(x3 + xr3), attv.w, p);                              \
        p += __shfl_xor(p, 8, 16);                                         \
        p += __shfl_xor(p, 4, 16);                                         \
        p += __shfl_xor(p, 2, 16);                                         \
        p += __shfl_xor(p, 1, 16);                                         \
        float wgt = exp2f(p);                                              \
        SS += wgt;                                                         \
        A0 = fmaf(wgt, x0, A0); A1 = fmaf(wgt, x1, A1);                    \
        A2 = fmaf(wgt, x2, A2); A3 = fmaf(wgt, x3, A3);                    \
    }

    int s0 = csr_src[rs];
    int s1 = (rs + 1 < re) ? csr_src[rs + 1] : s0;
    ushort4 xA = *(const ushort4*)&XL[(size_t)s0 * 128 + c0];
    ushort4 xB = *(const ushort4*)&XL[(size_t)s1 * 128 + c0];
    int j = rs;
    for (; j + 2 < re; j += 2) {
        int sA2 = csr_src[j + 2];
        int sB2 = (j + 3 < re) ? csr_src[j + 3] : sA2;
        ushort4 xA2 = *(const ushort4*)&XL[(size_t)sA2 * 128 + c0];
        ushort4 xB2 = *(const ushort4*)&XL[(size_t)sB2 * 128 + c0];
        PROC1(xA, sA, aA0, aA1, aA2, aA3);
        PROC1(xB, sB, aB0, aB1, aB2, aB3);
        xA = xA2; xB = xB2;
    }
    PROC1(xA, sA, aA0, aA1, aA2, aA3);
    if (j + 1 < re) PROC1(xB, sB, aB0, aB1, aB2, aB3);
#undef PROC1

    float inv = 1.0f / (sA + sB);
    float4 bv = *(const float4*)&bias[c0];
    float r0 = fmaf(aA0 + aB0, inv, bv.x), r1 = fmaf(aA1 + aB1, inv, bv.y);
    float r2 = fmaf(aA2 + aB2, inv, bv.z), r3 = fmaf(aA3 + aB3, inv, bv.w);
    ushort4 o;
    o.x = (unsigned short)f2bf(r0 > 0.f ? r0 : 0.f);
    o.y = (unsigned short)f2bf(r1 > 0.f ? r1 : 0.f);
    o.z = (unsigned short)f2bf(r2 > 0.f ? r2 : 0.f);
    o.w = (unsigned short)f2bf(r3 > 0.f ? r3 : 0.f);
    *(ushort4*)&H1[(size_t)d * 128 + c0] = o;
}

// ======= conv2 fused + pool (64 replicas) + out linear (last-block ticket) =======
__global__ __launch_bounds__(256) void node_conv2(const unsigned short* __restrict__ XL,
                                                  const unsigned short* __restrict__ XR,
                                                  const int* __restrict__ rowstart,
                                                  const int* __restrict__ csr_src,
                                                  const float* __restrict__ att,
                                                  const float* __restrict__ bias,
                                                  float* __restrict__ pooledR,
                                                  int* __restrict__ done_ctr,
                                                  const float* __restrict__ Wout,
                                                  const float* __restrict__ b_out,
                                                  float* __restrict__ out, int N) {
    __shared__ float psh[32];
    __shared__ int ticket;
    if (threadIdx.x < 32) psh[threadIdx.x] = 0.0f;
    __syncthreads();

    int slot = threadIdx.x >> 3;  // 0..31
    int l = threadIdx.x & 7;
    int c0 = 4 * l;
    float4 attv = *(const float4*)&att[c0];
    attv.x *= LOG2E; attv.y *= LOG2E; attv.z *= LOG2E; attv.w *= LOG2E;
    float4 bv = *(const float4*)&bias[c0];
    float p0 = 0.f, p1 = 0.f, p2 = 0.f, p3 = 0.f;

#define PROC2(xu, SS, A0, A1, A2, A3)                                      \
    {                                                                      \
        float x0 = bf2f(xu.x), x1 = bf2f(xu.y), x2 = bf2f(xu.z), x3 = bf2f(xu.w); \
        float p = leaky(x0 + xr0) * attv.x;                                \
        p = fmaf(leaky(x1 + xr1), attv.y, p);                              \
        p = fmaf(leaky(x2 + xr2), attv.z, p);                              \
        p = fmaf(leaky(x3 + xr3), attv.w, p);                              \
        p += __shfl_xor(p, 4, 8);                                          \
        p += __shfl_xor(p, 2, 8);                                          \
        p += __shfl_xor(p, 1, 8);                                          \
        float wgt = exp2f(p);                                              \
        SS += wgt;                                                         \
        A0 = fmaf(wgt, x0, A0); A1 = fmaf(wgt, x1, A1);                    \
        A2 = fmaf(wgt, x2, A2); A3 = fmaf(wgt, x3, A3);                    \
    }

    for (int d = blockIdx.x * 32 + slot; d < N; d += gridDim.x * 32) {
        int rs = rowstart[d], re = rowstart[d + 1];
        ushort4 xru = *(const ushort4*)&XR[(size_t)d * 32 + c0];
        float xr0 = bf2f(xru.x), xr1 = bf2f(xru.y), xr2 = bf2f(xru.z), xr3 = bf2f(xru.w);
        float sA = 0.f, aA0 = 0.f, aA1 = 0.f, aA2 = 0.f, aA3 = 0.f;
        float sB = 0.f, aB0 = 0.f, aB1 = 0.f, aB2 = 0.f, aB3 = 0.f;

        int s0 = csr_src[rs];
        int s1 = (rs + 1 < re) ? csr_src[rs + 1] : s0;
        ushort4 xA = *(const ushort4*)&XL[(size_t)s0 * 32 + c0];
        ushort4 xB = *(const ushort4*)&XL[(size_t)s1 * 32 + c0];
        int j = rs;
        for (; j + 2 < re; j += 2) {
            int sA2 = csr_src[j + 2];
            int sB2 = (j + 3 < re) ? csr_src[j + 3] : sA2;
            ushort4 xA2 = *(const ushort4*)&XL[(size_t)sA2 * 32 + c0];
            ushort4 xB2 = *(const ushort4*)&XL[(size_t)sB2 * 32 + c0];
            PROC2(xA, sA, aA0, aA1, aA2, aA3);
            PROC2(xB, sB, aB0, aB1, aB2, aB3);
            xA = xA2; xB = xB2;
        }
        PROC2(xA, sA, aA0, aA1, aA2, aA3);
        if (j + 1 < re) PROC2(xB, sB, aB0, aB1, aB2, aB3);

        float inv = 1.0f / (sA + sB);
        float r0 = fmaf(aA0 + aB0, inv, bv.x), r1 = fmaf(aA1 + aB1, inv, bv.y);
        float r2 = fmaf(aA2 + aB2, inv, bv.z), r3 = fmaf(aA3 + aB3, inv, bv.w);
        p0 += r0 > 0.f ? r0 : 0.f;
        p1 += r1 > 0.f ? r1 : 0.f;
        p2 += r2 > 0.f ? r2 : 0.f;
        p3 += r3 > 0.f ? r3 : 0.f;
    }
#undef PROC2
    atomicAdd(&psh[c0 + 0], p0);
    atomicAdd(&psh[c0 + 1], p1);
    atomicAdd(&psh[c0 + 2], p2);
    atomicAdd(&psh[c0 + 3], p3);
    __syncthreads();
    float* rep = pooledR + (blockIdx.x & (NREP - 1)) * 32;
    if (threadIdx.x < 32) atomicAdd(&rep[threadIdx.x], psh[threadIdx.x]);
    __threadfence();
    __syncthreads();
    if (threadIdx.x == 0) ticket = atomicAdd(done_ctr, 1);
    __syncthreads();
    if (ticket == (int)gridDim.x - 1) {
        __threadfence();
        if (threadIdx.x < 32) {
            float tot = 0.f;
#pragma unroll
            for (int r = 0; r < NREP; ++r)
                tot += __hip_atomic_load(&pooledR[r * 32 + threadIdx.x],
                                         __ATOMIC_RELAXED, __HIP_MEMORY_SCOPE_AGENT);
            psh[threadIdx.x] = tot;
        }
        __syncthreads();
        if (threadIdx.x < 96) {
            float invN = 1.0f / (float)N;
            float s = b_out[threadIdx.x];
#pragma unroll
            for (int c = 0; c < 32; ++c)
                s += (psh[c] * invN) * Wout[threadIdx.x * 32 + c];
            out[threadIdx.x] = s;
        }
    }
}

extern "C" void kernel_launch(void* const* d_in, const int* in_sizes, int n_in,
                              void* d_out, int out_size, void* d_ws, size_t ws_size,
                              hipStream_t stream) {
    const float* x     = (const float*)d_in[0];
    const int*   ei    = (const int*)d_in[1];
    const float* Win   = (const float*)d_in[3];
    const float* b_in  = (const float*)d_in[4];
    const float* Wl1   = (const float*)d_in[5];
    const float* bl1   = (const float*)d_in[6];
    const float* Wr1   = (const float*)d_in[7];
    const float* br1   = (const float*)d_in[8];
    const float* att1  = (const float*)d_in[9];
    const float* bias1 = (const float*)d_in[10];
    const float* Wl2   = (const float*)d_in[11];
    const float* bl2   = (const float*)d_in[12];
    const float* Wr2   = (const float*)d_in[13];
    const float* br2   = (const float*)d_in[14];
    const float* att2  = (const float*)d_in[15];
    const float* bias2 = (const float*)d_in[16];
    const float* Wout  = (const float*)d_in[17];
    const float* b_out = (const float*)d_in[18];
    float* out = (float*)d_out;

    int N = in_sizes[0] / 128;  // 50000
    int E = in_sizes[1] / 2;    // 600000
    int Etot = E + N;
    int nbt = (N + 255) / 256;

    char* wsb = (char*)d_ws;
    size_t off = 0;
    auto alloc = [&](size_t bytes) { void* p = wsb + off; off += (bytes + 255) & ~(size_t)255; return p; };

    unsigned short* XL1   = (unsigned short*)alloc((size_t)N * 128 * 2);  // reused as XL2
    unsigned short* XR1   = (unsigned short*)alloc((size_t)N * 128 * 2);  // reused as XR2
    unsigned short* H1    = (unsigned short*)alloc((size_t)N * 128 * 2);
    unsigned short* Wcat1 = (unsigned short*)alloc(256 * 128 * 2);
    unsigned short* Wcat2 = (unsigned short*)alloc(64 * 128 * 2);
    float* bcat1   = (float*)alloc(256 * 4);
    float* bcat2   = (float*)alloc(64 * 4);
    float* pooledR = (float*)alloc(NREP * 32 * 4);
    int* done_ctr  = (int*)alloc(4);
    int* rowstart  = (int*)alloc((size_t)(N + 1) * 4);
    int* deg       = (int*)alloc((size_t)N * 4);
    int* cursor    = (int*)alloc((size_t)N * 4);
    int* csr_src   = (int*)alloc((size_t)Etot * 4);
    int* partial   = (int*)alloc((size_t)nbt * 4);
    unsigned short* XL2 = XL1;
    unsigned short* XR2 = XR1;

    hipMemsetAsync(deg, 0, (size_t)N * 4, stream);

    // --- CSR build ---
    hist_kernel<<<(Etot + 255) / 256, 256, 0, stream>>>(ei, deg, E, Etot);
    blocksum_kernel<<<nbt, 256, 0, stream>>>(deg, partial, N);
    scanpartial_kernel<<<1, 256, 0, stream>>>(partial, nbt, rowstart, done_ctr, pooledR, N, Etot);
    scanfinal_kernel<<<nbt, 256, 0, stream>>>(deg, partial, rowstart, cursor, N);
    scatter_kernel<<<(Etot + 255) / 256, 256, 0, stream>>>(ei, cursor, csr_src, E, Etot);

    // --- weight prep (fold1 + cat2 in one kernel) ---
    fold1_kernel<<<288, 128, 0, stream>>>(Win, b_in, Wl1, bl1, Wr1, br1,
                                          Wl2, bl2, Wr2, br2, Wcat1, bcat1, Wcat2, bcat2);

    const int gb = (N + 63) / 64;
    // --- conv1 (cvt fused into gemm via f32 A path) ---
    gemm_mfma<4, 128, true><<<gb, 256, 0, stream>>>(x, Wcat1, bcat1, XL1, XR1, N);
    node_conv1<<<(N + 7) / 8, 256, 0, stream>>>(XL1, XR1, rowstart, csr_src, att1, bias1, H1, N);

    // --- conv2 (+pool+out fused) ---
    gemm_mfma<1, 32, false><<<gb, 256, 0, stream>>>(H1, Wcat2, bcat2, XL2, XR2, N);
    node_conv2<<<1280, 256, 0, stream>>>(XL2, XR2, rowstart, csr_src, att2, bias2,
                                         pooledR, done_ctr, Wout, b_out, out, N);
}

// Round 11
// 281.634 us; speedup vs baseline: 1.2553x; 1.2553x over previous
//
#include <hip/hip_runtime.h>
#include <hip/hip_bf16.h>
#include <math.h>

// GATv2 encoder, 12-kernel graph:
//   memset(deg) -> hist -> blocksum -> scanpartial(+zero pooledR) -> scanfinal
//   -> scatter -> fold1(+cat2) -> gemm1(mfma, f32 A) -> node_conv1(ring4)
//   -> gemm2(mfma, bf16 A) -> node_conv2(ring4, pool replicas, NO fence/ticket)
//   -> out_kernel (1 block; stream order provides visibility)
// R10 lesson: per-block __threadfence() serialized conv2 (dur ∝ blocks). Removed.

#define NEG_SLOPE 0.2f
#define LOG2E 1.4426950408889634f
#define NREP 16

typedef __attribute__((ext_vector_type(8))) short bf16x8;
typedef __attribute__((ext_vector_type(4))) float f32x4;

__device__ __forceinline__ float leaky(float t) { return fmaxf(t, NEG_SLOPE * t); }
__device__ __forceinline__ float bf2f(unsigned short u) {
    return __uint_as_float((unsigned)u << 16);
}
__device__ __forceinline__ short f2bf(float f) {
    __hip_bfloat16 h = __float2bfloat16(f);
    return *reinterpret_cast<short*>(&h);
}

// ---------------- CSR build ----------------
__global__ void hist_kernel(const int* __restrict__ ei, int* __restrict__ deg,
                            int E, int Etot) {
    int e = blockIdx.x * blockDim.x + threadIdx.x;
    if (e >= Etot) return;
    int d = (e < E) ? ei[E + e] : (e - E);
    atomicAdd(&deg[d], 1);
}

__global__ __launch_bounds__(256) void blocksum_kernel(const int* __restrict__ deg,
                                                       int* __restrict__ partial, int N) {
    __shared__ int sh[256];
    int i = blockIdx.x * 256 + threadIdx.x;
    sh[threadIdx.x] = (i < N) ? deg[i] : 0;
    __syncthreads();
    for (int off = 128; off > 0; off >>= 1) {
        if (threadIdx.x < off) sh[threadIdx.x] += sh[threadIdx.x + off];
        __syncthreads();
    }
    if (threadIdx.x == 0) partial[blockIdx.x] = sh[0];
}

__global__ __launch_bounds__(256) void scanpartial_kernel(int* partial, int nb,
                                                          int* rowstart, float* pooledR,
                                                          int N, int Etot) {
    __shared__ int sh[256];
    int t = threadIdx.x;
    for (int i = t; i < NREP * 32; i += 256) pooledR[i] = 0.f;
    int v = (t < nb) ? partial[t] : 0;
    sh[t] = v;
    __syncthreads();
    for (int off = 1; off < 256; off <<= 1) {
        int u = (t >= off) ? sh[t - off] : 0;
        __syncthreads();
        sh[t] += u;
        __syncthreads();
    }
    if (t < nb) partial[t] = sh[t] - v;
    if (t == 0) rowstart[N] = Etot;
}

__global__ __launch_bounds__(256) void scanfinal_kernel(const int* __restrict__ deg,
                                                        const int* __restrict__ partial,
                                                        int* __restrict__ rowstart,
                                                        int* __restrict__ cursor, int N) {
    __shared__ int sh[256];
    int i = blockIdx.x * 256 + threadIdx.x;
    int v = (i < N) ? deg[i] : 0;
    sh[threadIdx.x] = v;
    __syncthreads();
    for (int off = 1; off < 256; off <<= 1) {
        int t = (threadIdx.x >= off) ? sh[threadIdx.x - off] : 0;
        __syncthreads();
        sh[threadIdx.x] += t;
        __syncthreads();
    }
    if (i < N) {
        int ex = partial[blockIdx.x] + sh[threadIdx.x] - v;
        rowstart[i] = ex;
        cursor[i] = ex;
    }
}

__global__ void scatter_kernel(const int* __restrict__ ei, int* __restrict__ cursor,
                               int* __restrict__ csr_src, int E, int Etot) {
    int e = blockIdx.x * blockDim.x + threadIdx.x;
    if (e >= Etot) return;
    int s, d;
    if (e < E) { s = ei[e]; d = ei[E + e]; } else { s = d = e - E; }
    int pos = atomicAdd(&cursor[d], 1);
    csr_src[pos] = s;
}

// ---------------- weight prep: fold1 (b<256) + cat2 (b>=256) ----------------
__global__ __launch_bounds__(128) void fold1_kernel(const float* __restrict__ Win,
                                                    const float* __restrict__ b_in,
                                                    const float* __restrict__ Wl1,
                                                    const float* __restrict__ bl1,
                                                    const float* __restrict__ Wr1,
                                                    const float* __restrict__ br1,
                                                    const float* __restrict__ Wl2,
                                                    const float* __restrict__ bl2,
                                                    const float* __restrict__ Wr2,
                                                    const float* __restrict__ br2,
                                                    unsigned short* __restrict__ Wcat1,
                                                    float* __restrict__ bcat1,
                                                    unsigned short* __restrict__ Wcat2,
                                                    float* __restrict__ bcat2) {
    int b = blockIdx.x;
    int k = threadIdx.x;  // 0..127
    if (b >= 256) {
        int fb = b - 256;  // 0..31
        for (int i = fb * 128 + k; i < 64 * 128; i += 32 * 128) {
            int m = i >> 7, kk = i & 127;
            float v = (m < 32) ? Wl2[m * 128 + kk] : Wr2[(m - 32) * 128 + kk];
            Wcat2[i] = (unsigned short)f2bf(v);
        }
        if (fb == 0 && k < 64) bcat2[k] = (k < 32) ? bl2[k] : br2[k - 32];
        return;
    }
    int o = b;
    const float* Wx = (o < 128) ? Wl1 : Wr1;
    const float* bx = (o < 128) ? bl1 : br1;
    int oo = o & 127;
    float acc = 0.f;
#pragma unroll 16
    for (int j = 0; j < 128; ++j)
        acc = fmaf(Wx[oo * 128 + j], Win[j * 128 + k], acc);
    Wcat1[o * 128 + k] = (unsigned short)f2bf(acc);

    __shared__ float red[128];
    red[k] = Wx[oo * 128 + k] * b_in[k];
    __syncthreads();
    for (int off = 64; off > 0; off >>= 1) {
        if (k < off) red[k] += red[k + off];
        __syncthreads();
    }
    if (k == 0) bcat1[o] = red[0] + bx[oo];
}

// ---------------- MFMA GEMM ----------------
template <int CT, int S, bool A_F32>
__global__ __launch_bounds__(256) void gemm_mfma(const void* __restrict__ Av,
                                                 const unsigned short* __restrict__ W,
                                                 const float* __restrict__ bias,
                                                 unsigned short* __restrict__ OUT0,
                                                 unsigned short* __restrict__ OUT1,
                                                 int N) {
    const int w = threadIdx.x >> 6;
    const int lane = threadIdx.x & 63;
    const int ln = lane & 15;
    const int quad = lane >> 4;
    const int nb = blockIdx.x * 64;
    const int c0 = w * CT * 16;

    f32x4 acc[4][CT];
#pragma unroll
    for (int rt = 0; rt < 4; ++rt)
#pragma unroll
        for (int ct = 0; ct < CT; ++ct) acc[rt][ct] = (f32x4){0.f, 0.f, 0.f, 0.f};

    int rows[4];
#pragma unroll
    for (int rt = 0; rt < 4; ++rt) {
        int n = nb + rt * 16 + ln;
        rows[rt] = n < N ? n : N - 1;
    }

#pragma unroll
    for (int kc = 0; kc < 4; ++kc) {
        const int k0 = kc * 32 + quad * 8;
        bf16x8 a[4], wv[CT];
#pragma unroll
        for (int rt = 0; rt < 4; ++rt) {
            if (A_F32) {
                const float* p = (const float*)Av + (size_t)rows[rt] * 128 + k0;
                float4 u = *(const float4*)p;
                float4 v = *(const float4*)(p + 4);
                a[rt][0] = f2bf(u.x); a[rt][1] = f2bf(u.y);
                a[rt][2] = f2bf(u.z); a[rt][3] = f2bf(u.w);
                a[rt][4] = f2bf(v.x); a[rt][5] = f2bf(v.y);
                a[rt][6] = f2bf(v.z); a[rt][7] = f2bf(v.w);
            } else {
                a[rt] = *(const bf16x8*)((const unsigned short*)Av + (size_t)rows[rt] * 128 + k0);
            }
        }
#pragma unroll
        for (int ct = 0; ct < CT; ++ct)
            wv[ct] = *(const bf16x8*)(W + (size_t)(c0 + ct * 16 + ln) * 128 + k0);
#pragma unroll
        for (int rt = 0; rt < 4; ++rt)
#pragma unroll
            for (int ct = 0; ct < CT; ++ct)
                acc[rt][ct] = __builtin_amdgcn_mfma_f32_16x16x32_bf16(wv[ct], a[rt], acc[rt][ct], 0, 0, 0);
    }

#pragma unroll
    for (int rt = 0; rt < 4; ++rt) {
        int n = nb + rt * 16 + ln;
        if (n >= N) continue;
#pragma unroll
        for (int ct = 0; ct < CT; ++ct) {
            int cb = c0 + ct * 16 + quad * 4;
            float4 bv = *(const float4*)&bias[cb];
            ushort4 o;
            o.x = (unsigned short)f2bf(acc[rt][ct][0] + bv.x);
            o.y = (unsigned short)f2bf(acc[rt][ct][1] + bv.y);
            o.z = (unsigned short)f2bf(acc[rt][ct][2] + bv.z);
            o.w = (unsigned short)f2bf(acc[rt][ct][3] + bv.w);
            if (cb < S) *(ushort4*)&OUT0[(size_t)n * S + cb] = o;
            else        *(ushort4*)&OUT1[(size_t)n * S + cb - S] = o;
        }
    }
}

// ================= conv1 fused: 32 lanes/node, 4-deep gather ring =================
__global__ __launch_bounds__(256) void node_conv1(const unsigned short* __restrict__ XL,
                                                  const unsigned short* __restrict__ XR,
                                                  const int* __restrict__ rowstart,
                                                  const int* __restrict__ csr_src,
                                                  const float* __restrict__ att,
                                                  const float* __restrict__ bias,
                                                  unsigned short* __restrict__ H1, int N) {
    int d = blockIdx.x * 8 + (threadIdx.x >> 5);
    if (d >= N) return;
    int l = threadIdx.x & 31;
    int c0 = 4 * l;
    int rs = rowstart[d], re = rowstart[d + 1];

    float4 attv = *(const float4*)&att[c0];
    attv.x *= LOG2E; attv.y *= LOG2E; attv.z *= LOG2E; attv.w *= LOG2E;
    ushort4 xru = *(const ushort4*)&XR[(size_t)d * 128 + c0];
    float xr0 = bf2f(xru.x), xr1 = bf2f(xru.y), xr2 = bf2f(xru.z), xr3 = bf2f(xru.w);

    float ssum = 0.f, a0 = 0.f, a1 = 0.f, a2 = 0.f, a3 = 0.f;

#define LOADX1(j) (*(const ushort4*)&XL[(size_t)csr_src[(j) < re ? (j) : re - 1] * 128 + c0])
#define PROC1(xu)                                                          \
    {                                                                      \
        float x0 = bf2f(xu.x), x1 = bf2f(xu.y), x2 = bf2f(xu.z), x3 = bf2f(xu.w); \
        float p = leaky(x0 + xr0) * attv.x;                                \
        p = fmaf(leaky(x1 + xr1), attv.y, p);                              \
        p = fmaf(leaky(x2 + xr2), attv.z, p);                              \
        p = fmaf(leaky(x3 + xr3), attv.w, p);                              \
        p += __shfl_xor(p, 8, 16);                                         \
        p += __shfl_xor(p, 4, 16);                                         \
        p += __shfl_xor(p, 2, 16);                                         \
        p += __shfl_xor(p, 1, 16);                                         \
        float wgt = exp2f(p);                                              \
        ssum += wgt;                                                       \
        a0 = fmaf(wgt, x0, a0); a1 = fmaf(wgt, x1, a1);                    \
        a2 = fmaf(wgt, x2, a2); a3 = fmaf(wgt, x3, a3);                    \
    }

    ushort4 b0 = LOADX1(rs), b1 = LOADX1(rs + 1), b2 = LOADX1(rs + 2), b3 = LOADX1(rs + 3);
    for (int j = rs; j < re; j += 4) {
        ushort4 n0 = LOADX1(j + 4), n1 = LOADX1(j + 5), n2 = LOADX1(j + 6), n3 = LOADX1(j + 7);
        PROC1(b0);
        if (j + 1 < re) PROC1(b1);
        if (j + 2 < re) PROC1(b2);
        if (j + 3 < re) PROC1(b3);
        b0 = n0; b1 = n1; b2 = n2; b3 = n3;
    }
#undef PROC1
#undef LOADX1

    float inv = 1.0f / ssum;
    float4 bv = *(const float4*)&bias[c0];
    float r0 = fmaf(a0, inv, bv.x), r1 = fmaf(a1, inv, bv.y);
    float r2 = fmaf(a2, inv, bv.z), r3 = fmaf(a3, inv, bv.w);
    ushort4 o;
    o.x = (unsigned short)f2bf(r0 > 0.f ? r0 : 0.f);
    o.y = (unsigned short)f2bf(r1 > 0.f ? r1 : 0.f);
    o.z = (unsigned short)f2bf(r2 > 0.f ? r2 : 0.f);
    o.w = (unsigned short)f2bf(r3 > 0.f ? r3 : 0.f);
    *(ushort4*)&H1[(size_t)d * 128 + c0] = o;
}

// ====== conv2 fused + pool (replicas, device atomics, NO fence/ticket) ======
__global__ __launch_bounds__(256) void node_conv2(const unsigned short* __restrict__ XL,
                                                  const unsigned short* __restrict__ XR,
                                                  const int* __restrict__ rowstart,
                                                  const int* __restrict__ csr_src,
                                                  const float* __restrict__ att,
                                                  const float* __restrict__ bias,
                                                  float* __restrict__ pooledR, int N) {
    __shared__ float psh[32];
    if (threadIdx.x < 32) psh[threadIdx.x] = 0.0f;
    __syncthreads();

    int slot = threadIdx.x >> 3;  // 0..31
    int l = threadIdx.x & 7;
    int c0 = 4 * l;
    float4 attv = *(const float4*)&att[c0];
    attv.x *= LOG2E; attv.y *= LOG2E; attv.z *= LOG2E; attv.w *= LOG2E;
    float4 bv = *(const float4*)&bias[c0];
    float p0 = 0.f, p1 = 0.f, p2 = 0.f, p3 = 0.f;

#define LOADX2(j) (*(const ushort4*)&XL[(size_t)csr_src[(j) < re ? (j) : re - 1] * 32 + c0])
#define PROC2(xu)                                                          \
    {                                                                      \
        float x0 = bf2f(xu.x), x1 = bf2f(xu.y), x2 = bf2f(xu.z), x3 = bf2f(xu.w); \
        float p = leaky(x0 + xr0) * attv.x;                                \
        p = fmaf(leaky(x1 + xr1), attv.y, p);                              \
        p = fmaf(leaky(x2 + xr2), attv.z, p);                              \
        p = fmaf(leaky(x3 + xr3), attv.w, p);                              \
        p += __shfl_xor(p, 4, 8);                                          \
        p += __shfl_xor(p, 2, 8);                                          \
        p += __shfl_xor(p, 1, 8);                                          \
        float wgt = exp2f(p);                                              \
        ssum += wgt;                                                       \
        a0 = fmaf(wgt, x0, a0); a1 = fmaf(wgt, x1, a1);                    \
        a2 = fmaf(wgt, x2, a2); a3 = fmaf(wgt, x3, a3);                    \
    }

    for (int d = blockIdx.x * 32 + slot; d < N; d += gridDim.x * 32) {
        int rs = rowstart[d], re = rowstart[d + 1];
        ushort4 xru = *(const ushort4*)&XR[(size_t)d * 32 + c0];
        float xr0 = bf2f(xru.x), xr1 = bf2f(xru.y), xr2 = bf2f(xru.z), xr3 = bf2f(xru.w);
        float ssum = 0.f, a0 = 0.f, a1 = 0.f, a2 = 0.f, a3 = 0.f;

        ushort4 b0 = LOADX2(rs), b1 = LOADX2(rs + 1), b2 = LOADX2(rs + 2), b3 = LOADX2(rs + 3);
        for (int j = rs; j < re; j += 4) {
            ushort4 n0 = LOADX2(j + 4), n1 = LOADX2(j + 5), n2 = LOADX2(j + 6), n3 = LOADX2(j + 7);
            PROC2(b0);
            if (j + 1 < re) PROC2(b1);
            if (j + 2 < re) PROC2(b2);
            if (j + 3 < re) PROC2(b3);
            b0 = n0; b1 = n1; b2 = n2; b3 = n3;
        }

        float inv = 1.0f / ssum;
        float r0 = fmaf(a0, inv, bv.x), r1 = fmaf(a1, inv, bv.y);
        float r2 = fmaf(a2, inv, bv.z), r3 = fmaf(a3, inv, bv.w);
        p0 += r0 > 0.f ? r0 : 0.f;
        p1 += r1 > 0.f ? r1 : 0.f;
        p2 += r2 > 0.f ? r2 : 0.f;
        p3 += r3 > 0.f ? r3 : 0.f;
    }
#undef PROC2
#undef LOADX2
    atomicAdd(&psh[c0 + 0], p0);
    atomicAdd(&psh[c0 + 1], p1);
    atomicAdd(&psh[c0 + 2], p2);
    atomicAdd(&psh[c0 + 3], p3);
    __syncthreads();
    float* rep = pooledR + (blockIdx.x & (NREP - 1)) * 32;
    if (threadIdx.x < 32) atomicAdd(&rep[threadIdx.x], psh[threadIdx.x]);
}

__global__ void out_kernel(const float* __restrict__ pooledR, const float* __restrict__ Wout,
                           const float* __restrict__ b_out, float* __restrict__ out, int N) {
    __shared__ float psum[32];
    if (threadIdx.x < 32) {
        float tot = 0.f;
#pragma unroll
        for (int r = 0; r < NREP; ++r) tot += pooledR[r * 32 + threadIdx.x];
        psum[threadIdx.x] = tot;
    }
    __syncthreads();
    int m = threadIdx.x;
    if (m < 96) {
        float invN = 1.0f / (float)N;
        float s = b_out[m];
#pragma unroll
        for (int c = 0; c < 32; ++c) s += (psum[c] * invN) * Wout[m * 32 + c];
        out[m] = s;
    }
}

extern "C" void kernel_launch(void* const* d_in, const int* in_sizes, int n_in,
                              void* d_out, int out_size, void* d_ws, size_t ws_size,
                              hipStream_t stream) {
    const float* x     = (const float*)d_in[0];
    const int*   ei    = (const int*)d_in[1];
    const float* Win   = (const float*)d_in[3];
    const float* b_in  = (const float*)d_in[4];
    const float* Wl1   = (const float*)d_in[5];
    const float* bl1   = (const float*)d_in[6];
    const float* Wr1   = (const float*)d_in[7];
    const float* br1   = (const float*)d_in[8];
    const float* att1  = (const float*)d_in[9];
    const float* bias1 = (const float*)d_in[10];
    const float* Wl2   = (const float*)d_in[11];
    const float* bl2   = (const float*)d_in[12];
    const float* Wr2   = (const float*)d_in[13];
    const float* br2   = (const float*)d_in[14];
    const float* att2  = (const float*)d_in[15];
    const float* bias2 = (const float*)d_in[16];
    const float* Wout  = (const float*)d_in[17];
    const float* b_out = (const float*)d_in[18];
    float* out = (float*)d_out;

    int N = in_sizes[0] / 128;  // 50000
    int E = in_sizes[1] / 2;    // 600000
    int Etot = E + N;
    int nbt = (N + 255) / 256;

    char* wsb = (char*)d_ws;
    size_t off = 0;
    auto alloc = [&](size_t bytes) { void* p = wsb + off; off += (bytes + 255) & ~(size_t)255; return p; };

    unsigned short* XL1   = (unsigned short*)alloc((size_t)N * 128 * 2);  // reused as XL2
    unsigned short* XR1   = (unsigned short*)alloc((size_t)N * 128 * 2);  // reused as XR2
    unsigned short* H1    = (unsigned short*)alloc((size_t)N * 128 * 2);
    unsigned short* Wcat1 = (unsigned short*)alloc(256 * 128 * 2);
    unsigned short* Wcat2 = (unsigned short*)alloc(64 * 128 * 2);
    float* bcat1   = (float*)alloc(256 * 4);
    float* bcat2   = (float*)alloc(64 * 4);
    float* pooledR = (float*)alloc(NREP * 32 * 4);
    int* rowstart  = (int*)alloc((size_t)(N + 1) * 4);
    int* deg       = (int*)alloc((size_t)N * 4);
    int* cursor    = (int*)alloc((size_t)N * 4);
    int* csr_src   = (int*)alloc((size_t)Etot * 4);
    int* partial   = (int*)alloc((size_t)nbt * 4);
    unsigned short* XL2 = XL1;
    unsigned short* XR2 = XR1;

    hipMemsetAsync(deg, 0, (size_t)N * 4, stream);

    // --- CSR build ---
    hist_kernel<<<(Etot + 255) / 256, 256, 0, stream>>>(ei, deg, E, Etot);
    blocksum_kernel<<<nbt, 256, 0, stream>>>(deg, partial, N);
    scanpartial_kernel<<<1, 256, 0, stream>>>(partial, nbt, rowstart, pooledR, N, Etot);
    scanfinal_kernel<<<nbt, 256, 0, stream>>>(deg, partial, rowstart, cursor, N);
    scatter_kernel<<<(Etot + 255) / 256, 256, 0, stream>>>(ei, cursor, csr_src, E, Etot);

    // --- weight prep ---
    fold1_kernel<<<288, 128, 0, stream>>>(Win, b_in, Wl1, bl1, Wr1, br1,
                                          Wl2, bl2, Wr2, br2, Wcat1, bcat1, Wcat2, bcat2);

    const int gb = (N + 63) / 64;
    // --- conv1 ---
    gemm_mfma<4, 128, true><<<gb, 256, 0, stream>>>(x, Wcat1, bcat1, XL1, XR1, N);
    node_conv1<<<(N + 7) / 8, 256, 0, stream>>>(XL1, XR1, rowstart, csr_src, att1, bias1, H1, N);

    // --- conv2 ---
    gemm_mfma<1, 32, false><<<gb, 256, 0, stream>>>(H1, Wcat2, bcat2, XL2, XR2, N);
    node_conv2<<<640, 256, 0, stream>>>(XL2, XR2, rowstart, csr_src, att2, bias2, pooledR, N);

    // --- out ---
    out_kernel<<<1, 128, 0, stream>>>(pooledR, Wout, b_out, out, N);
}

// Round 12
// 275.966 us; speedup vs baseline: 1.2811x; 1.0205x over previous
//
#include <hip/hip_runtime.h>
#include <hip/hip_bf16.h>
#include <math.h>

// GATv2 encoder, 11-kernel graph:
//   memset(deg) -> hist -> blocksum(+zero pooledR) -> scanfinal(fused partial-scan)
//   -> scatter -> fold1(+cat2) -> gemm1(mfma, f32 A, 32-row blocks) -> node_conv1(ring4)
//   -> gemm2(mfma, bf16 A) -> node_conv2(ring4, replicas, no fence) -> out
// R10/R11 lessons: per-block __threadfence serializes (dur ∝ blocks) — avoid;
// grid.sync costs ~60us — avoid cooperative launch.

#define NEG_SLOPE 0.2f
#define LOG2E 1.4426950408889634f
#define NREP 16

typedef __attribute__((ext_vector_type(8))) short bf16x8;
typedef __attribute__((ext_vector_type(4))) float f32x4;

__device__ __forceinline__ float leaky(float t) { return fmaxf(t, NEG_SLOPE * t); }
__device__ __forceinline__ float bf2f(unsigned short u) {
    return __uint_as_float((unsigned)u << 16);
}
__device__ __forceinline__ short f2bf(float f) {
    __hip_bfloat16 h = __float2bfloat16(f);
    return *reinterpret_cast<short*>(&h);
}

// ---------------- CSR build ----------------
__global__ void hist_kernel(const int* __restrict__ ei, int* __restrict__ deg,
                            int E, int Etot) {
    int e = blockIdx.x * blockDim.x + threadIdx.x;
    if (e >= Etot) return;
    int d = (e < E) ? ei[E + e] : (e - E);
    atomicAdd(&deg[d], 1);
}

__global__ __launch_bounds__(256) void blocksum_kernel(const int* __restrict__ deg,
                                                       int* __restrict__ partial,
                                                       float* __restrict__ pooledR, int N) {
    __shared__ int sh[256];
    int i = blockIdx.x * 256 + threadIdx.x;
    if (blockIdx.x == 0) {
        for (int k = threadIdx.x; k < NREP * 32; k += 256) pooledR[k] = 0.f;
    }
    sh[threadIdx.x] = (i < N) ? deg[i] : 0;
    __syncthreads();
    for (int off = 128; off > 0; off >>= 1) {
        if (threadIdx.x < off) sh[threadIdx.x] += sh[threadIdx.x + off];
        __syncthreads();
    }
    if (threadIdx.x == 0) partial[blockIdx.x] = sh[0];
}

// fused: every block scans the (<=256) partials in LDS, then its own tile.
__global__ __launch_bounds__(256) void scanfinal_kernel(const int* __restrict__ deg,
                                                        const int* __restrict__ partial,
                                                        int* __restrict__ rowstart,
                                                        int* __restrict__ cursor,
                                                        int N, int nbt, int Etot) {
    __shared__ int shp[256];
    __shared__ int sh[256];
    int t = threadIdx.x, b = blockIdx.x;
    shp[t] = (t < nbt) ? partial[t] : 0;
    __syncthreads();
    for (int off = 1; off < 256; off <<= 1) {
        int u = (t >= off) ? shp[t - off] : 0;
        __syncthreads();
        shp[t] += u;
        __syncthreads();
    }
    int base = (b == 0) ? 0 : shp[b - 1];

    int i = b * 256 + t;
    int v = (i < N) ? deg[i] : 0;
    sh[t] = v;
    __syncthreads();
    for (int off = 1; off < 256; off <<= 1) {
        int u = (t >= off) ? sh[t - off] : 0;
        __syncthreads();
        sh[t] += u;
        __syncthreads();
    }
    if (i < N) {
        int ex = base + sh[t] - v;
        rowstart[i] = ex;
        cursor[i] = ex;
    }
    if (b == nbt - 1 && t == 0) rowstart[N] = Etot;
}

__global__ void scatter_kernel(const int* __restrict__ ei, int* __restrict__ cursor,
                               int* __restrict__ csr_src, int E, int Etot) {
    int e = blockIdx.x * blockDim.x + threadIdx.x;
    if (e >= Etot) return;
    int s, d;
    if (e < E) { s = ei[e]; d = ei[E + e]; } else { s = d = e - E; }
    int pos = atomicAdd(&cursor[d], 1);
    csr_src[pos] = s;
}

// ---------------- weight prep: fold1 (b<256) + cat2 (b>=256) ----------------
__global__ __launch_bounds__(128) void fold1_kernel(const float* __restrict__ Win,
                                                    const float* __restrict__ b_in,
                                                    const float* __restrict__ Wl1,
                                                    const float* __restrict__ bl1,
                                                    const float* __restrict__ Wr1,
                                                    const float* __restrict__ br1,
                                                    const float* __restrict__ Wl2,
                                                    const float* __restrict__ bl2,
                                                    const float* __restrict__ Wr2,
                                                    const float* __restrict__ br2,
                                                    unsigned short* __restrict__ Wcat1,
                                                    float* __restrict__ bcat1,
                                                    unsigned short* __restrict__ Wcat2,
                                                    float* __restrict__ bcat2) {
    int b = blockIdx.x;
    int k = threadIdx.x;  // 0..127
    if (b >= 256) {
        int fb = b - 256;  // 0..31
        for (int i = fb * 128 + k; i < 64 * 128; i += 32 * 128) {
            int m = i >> 7, kk = i & 127;
            float v = (m < 32) ? Wl2[m * 128 + kk] : Wr2[(m - 32) * 128 + kk];
            Wcat2[i] = (unsigned short)f2bf(v);
        }
        if (fb == 0 && k < 64) bcat2[k] = (k < 32) ? bl2[k] : br2[k - 32];
        return;
    }
    int o = b;
    const float* Wx = (o < 128) ? Wl1 : Wr1;
    const float* bx = (o < 128) ? bl1 : br1;
    int oo = o & 127;
    float acc = 0.f;
#pragma unroll 16
    for (int j = 0; j < 128; ++j)
        acc = fmaf(Wx[oo * 128 + j], Win[j * 128 + k], acc);
    Wcat1[o * 128 + k] = (unsigned short)f2bf(acc);

    __shared__ float red[128];
    red[k] = Wx[oo * 128 + k] * b_in[k];
    __syncthreads();
    for (int off = 64; off > 0; off >>= 1) {
        if (k < off) red[k] += red[k + off];
        __syncthreads();
    }
    if (k == 0) bcat1[o] = red[0] + bx[oo];
}

// ---------------- MFMA GEMM ----------------
// Block = 4 waves, RT*16 rows x 4*CT*16 ch.
template <int RT, int CT, int S, bool A_F32>
__global__ __launch_bounds__(256) void gemm_mfma(const void* __restrict__ Av,
                                                 const unsigned short* __restrict__ W,
                                                 const float* __restrict__ bias,
                                                 unsigned short* __restrict__ OUT0,
                                                 unsigned short* __restrict__ OUT1,
                                                 int N) {
    const int w = threadIdx.x >> 6;
    const int lane = threadIdx.x & 63;
    const int ln = lane & 15;
    const int quad = lane >> 4;
    const int nb = blockIdx.x * (RT * 16);
    const int c0 = w * CT * 16;

    f32x4 acc[RT][CT];
#pragma unroll
    for (int rt = 0; rt < RT; ++rt)
#pragma unroll
        for (int ct = 0; ct < CT; ++ct) acc[rt][ct] = (f32x4){0.f, 0.f, 0.f, 0.f};

    int rows[RT];
#pragma unroll
    for (int rt = 0; rt < RT; ++rt) {
        int n = nb + rt * 16 + ln;
        rows[rt] = n < N ? n : N - 1;
    }

#pragma unroll
    for (int kc = 0; kc < 4; ++kc) {
        const int k0 = kc * 32 + quad * 8;
        bf16x8 a[RT], wv[CT];
#pragma unroll
        for (int rt = 0; rt < RT; ++rt) {
            if (A_F32) {
                const float* p = (const float*)Av + (size_t)rows[rt] * 128 + k0;
                float4 u = *(const float4*)p;
                float4 v = *(const float4*)(p + 4);
                a[rt][0] = f2bf(u.x); a[rt][1] = f2bf(u.y);
                a[rt][2] = f2bf(u.z); a[rt][3] = f2bf(u.w);
                a[rt][4] = f2bf(v.x); a[rt][5] = f2bf(v.y);
                a[rt][6] = f2bf(v.z); a[rt][7] = f2bf(v.w);
            } else {
                a[rt] = *(const bf16x8*)((const unsigned short*)Av + (size_t)rows[rt] * 128 + k0);
            }
        }
#pragma unroll
        for (int ct = 0; ct < CT; ++ct)
            wv[ct] = *(const bf16x8*)(W + (size_t)(c0 + ct * 16 + ln) * 128 + k0);
#pragma unroll
        for (int rt = 0; rt < RT; ++rt)
#pragma unroll
            for (int ct = 0; ct < CT; ++ct)
                acc[rt][ct] = __builtin_amdgcn_mfma_f32_16x16x32_bf16(wv[ct], a[rt], acc[rt][ct], 0, 0, 0);
    }

#pragma unroll
    for (int rt = 0; rt < RT; ++rt) {
        int n = nb + rt * 16 + ln;
        if (n >= N) continue;
#pragma unroll
        for (int ct = 0; ct < CT; ++ct) {
            int cb = c0 + ct * 16 + quad * 4;
            float4 bv = *(const float4*)&bias[cb];
            ushort4 o;
            o.x = (unsigned short)f2bf(acc[rt][ct][0] + bv.x);
            o.y = (unsigned short)f2bf(acc[rt][ct][1] + bv.y);
            o.z = (unsigned short)f2bf(acc[rt][ct][2] + bv.z);
            o.w = (unsigned short)f2bf(acc[rt][ct][3] + bv.w);
            if (cb < S) *(ushort4*)&OUT0[(size_t)n * S + cb] = o;
            else        *(ushort4*)&OUT1[(size_t)n * S + cb - S] = o;
        }
    }
}

// ================= conv1 fused: 32 lanes/node, 4-deep gather ring =================
__global__ __launch_bounds__(256) void node_conv1(const unsigned short* __restrict__ XL,
                                                  const unsigned short* __restrict__ XR,
                                                  const int* __restrict__ rowstart,
                                                  const int* __restrict__ csr_src,
                                                  const float* __restrict__ att,
                                                  const float* __restrict__ bias,
                                                  unsigned short* __restrict__ H1, int N) {
    int d = blockIdx.x * 8 + (threadIdx.x >> 5);
    if (d >= N) return;
    int l = threadIdx.x & 31;
    int c0 = 4 * l;
    int rs = rowstart[d], re = rowstart[d + 1];

    float4 attv = *(const float4*)&att[c0];
    attv.x *= LOG2E; attv.y *= LOG2E; attv.z *= LOG2E; attv.w *= LOG2E;
    ushort4 xru = *(const ushort4*)&XR[(size_t)d * 128 + c0];
    float xr0 = bf2f(xru.x), xr1 = bf2f(xru.y), xr2 = bf2f(xru.z), xr3 = bf2f(xru.w);

    float ssum = 0.f, a0 = 0.f, a1 = 0.f, a2 = 0.f, a3 = 0.f;

#define LOADX1(j) (*(const ushort4*)&XL[(size_t)csr_src[(j) < re ? (j) : re - 1] * 128 + c0])
#define PROC1(xu)                                                          \
    {                                                                      \
        float x0 = bf2f(xu.x), x1 = bf2f(xu.y), x2 = bf2f(xu.z), x3 = bf2f(xu.w); \
        float p = leaky(x0 + xr0) * attv.x;                                \
        p = fmaf(leaky(x1 + xr1), attv.y, p);                              \
        p = fmaf(leaky(x2 + xr2), attv.z, p);                              \
        p = fmaf(leaky(x3 + xr3), attv.w, p);                              \
        p += __shfl_xor(p, 8, 16);                                         \
        p += __shfl_xor(p, 4, 16);                                         \
        p += __shfl_xor(p, 2, 16);                                         \
        p += __shfl_xor(p, 1, 16);                                         \
        float wgt = exp2f(p);                                              \
        ssum += wgt;                                                       \
        a0 = fmaf(wgt, x0, a0); a1 = fmaf(wgt, x1, a1);                    \
        a2 = fmaf(wgt, x2, a2); a3 = fmaf(wgt, x3, a3);                    \
    }

    ushort4 b0 = LOADX1(rs), b1 = LOADX1(rs + 1), b2 = LOADX1(rs + 2), b3 = LOADX1(rs + 3);
    for (int j = rs; j < re; j += 4) {
        ushort4 n0 = LOADX1(j + 4), n1 = LOADX1(j + 5), n2 = LOADX1(j + 6), n3 = LOADX1(j + 7);
        PROC1(b0);
        if (j + 1 < re) PROC1(b1);
        if (j + 2 < re) PROC1(b2);
        if (j + 3 < re) PROC1(b3);
        b0 = n0; b1 = n1; b2 = n2; b3 = n3;
    }
#undef PROC1
#undef LOADX1

    float inv = 1.0f / ssum;
    float4 bv = *(const float4*)&bias[c0];
    float r0 = fmaf(a0, inv, bv.x), r1 = fmaf(a1, inv, bv.y);
    float r2 = fmaf(a2, inv, bv.z), r3 = fmaf(a3, inv, bv.w);
    ushort4 o;
    o.x = (unsigned short)f2bf(r0 > 0.f ? r0 : 0.f);
    o.y = (unsigned short)f2bf(r1 > 0.f ? r1 : 0.f);
    o.z = (unsigned short)f2bf(r2 > 0.f ? r2 : 0.f);
    o.w = (unsigned short)f2bf(r3 > 0.f ? r3 : 0.f);
    *(ushort4*)&H1[(size_t)d * 128 + c0] = o;
}

// ====== conv2 fused + pool (replicas, device atomics, NO fence/ticket) ======
__global__ __launch_bounds__(256) void node_conv2(const unsigned short* __restrict__ XL,
                                                  const unsigned short* __restrict__ XR,
                                                  const int* __restrict__ rowstart,
                                                  const int* __restrict__ csr_src,
                                                  const float* __restrict__ att,
                                                  const float* __restrict__ bias,
                                                  float* __restrict__ pooledR, int N) {
    __shared__ float psh[32];
    if (threadIdx.x < 32) psh[threadIdx.x] = 0.0f;
    __syncthreads();

    int slot = threadIdx.x >> 3;  // 0..31
    int l = threadIdx.x & 7;
    int c0 = 4 * l;
    float4 attv = *(const float4*)&att[c0];
    attv.x *= LOG2E; attv.y *= LOG2E; attv.z *= LOG2E; attv.w *= LOG2E;
    float4 bv = *(const float4*)&bias[c0];
    float p0 = 0.f, p1 = 0.f, p2 = 0.f, p3 = 0.f;

#define LOADX2(j) (*(const ushort4*)&XL[(size_t)csr_src[(j) < re ? (j) : re - 1] * 32 + c0])
#define PROC2(xu)                                                          \
    {                                                                      \
        float x0 = bf2f(xu.x), x1 = bf2f(xu.y), x2 = bf2f(xu.z), x3 = bf2f(xu.w); \
        float p = leaky(x0 + xr0) * attv.x;                                \
        p = fmaf(leaky(x1 + xr1), attv.y, p);                              \
        p = fmaf(leaky(x2 + xr2), attv.z, p);                              \
        p = fmaf(leaky(x3 + xr3), attv.w, p);                              \
        p += __shfl_xor(p, 4, 8);                                          \
        p += __shfl_xor(p, 2, 8);                                          \
        p += __shfl_xor(p, 1, 8);                                          \
        float wgt = exp2f(p);                                              \
        ssum += wgt;                                                       \
        a0 = fmaf(wgt, x0, a0); a1 = fmaf(wgt, x1, a1);                    \
        a2 = fmaf(wgt, x2, a2); a3 = fmaf(wgt, x3, a3);                    \
    }

    for (int d = blockIdx.x * 32 + slot; d < N; d += gridDim.x * 32) {
        int rs = rowstart[d], re = rowstart[d + 1];
        ushort4 xru = *(const ushort4*)&XR[(size_t)d * 32 + c0];
        float xr0 = bf2f(xru.x), xr1 = bf2f(xru.y), xr2 = bf2f(xru.z), xr3 = bf2f(xru.w);
        float ssum = 0.f, a0 = 0.f, a1 = 0.f, a2 = 0.f, a3 = 0.f;

        ushort4 b0 = LOADX2(rs), b1 = LOADX2(rs + 1), b2 = LOADX2(rs + 2), b3 = LOADX2(rs + 3);
        for (int j = rs; j < re; j += 4) {
            ushort4 n0 = LOADX2(j + 4), n1 = LOADX2(j + 5), n2 = LOADX2(j + 6), n3 = LOADX2(j + 7);
            PROC2(b0);
            if (j + 1 < re) PROC2(b1);
            if (j + 2 < re) PROC2(b2);
            if (j + 3 < re) PROC2(b3);
            b0 = n0; b1 = n1; b2 = n2; b3 = n3;
        }

        float inv = 1.0f / ssum;
        float r0 = fmaf(a0, inv, bv.x), r1 = fmaf(a1, inv, bv.y);
        float r2 = fmaf(a2, inv, bv.z), r3 = fmaf(a3, inv, bv.w);
        p0 += r0 > 0.f ? r0 : 0.f;
        p1 += r1 > 0.f ? r1 : 0.f;
        p2 += r2 > 0.f ? r2 : 0.f;
        p3 += r3 > 0.f ? r3 : 0.f;
    }
#undef PROC2
#undef LOADX2
    atomicAdd(&psh[c0 + 0], p0);
    atomicAdd(&psh[c0 + 1], p1);
    atomicAdd(&psh[c0 + 2], p2);
    atomicAdd(&psh[c0 + 3], p3);
    __syncthreads();
    float* rep = pooledR + (blockIdx.x & (NREP - 1)) * 32;
    if (threadIdx.x < 32) atomicAdd(&rep[threadIdx.x], psh[threadIdx.x]);
}

__global__ void out_kernel(const float* __restrict__ pooledR, const float* __restrict__ Wout,
                           const float* __restrict__ b_out, float* __restrict__ out, int N) {
    __shared__ float psum[32];
    if (threadIdx.x < 32) {
        float tot = 0.f;
#pragma unroll
        for (int r = 0; r < NREP; ++r) tot += pooledR[r * 32 + threadIdx.x];
        psum[threadIdx.x] = tot;
    }
    __syncthreads();
    int m = threadIdx.x;
    if (m < 96) {
        float invN = 1.0f / (float)N;
        float s = b_out[m];
#pragma unroll
        for (int c = 0; c < 32; ++c) s += (psum[c] * invN) * Wout[m * 32 + c];
        out[m] = s;
    }
}

extern "C" void kernel_launch(void* const* d_in, const int* in_sizes, int n_in,
                              void* d_out, int out_size, void* d_ws, size_t ws_size,
                              hipStream_t stream) {
    const float* x     = (const float*)d_in[0];
    const int*   ei    = (const int*)d_in[1];
    const float* Win   = (const float*)d_in[3];
    const float* b_in  = (const float*)d_in[4];
    const float* Wl1   = (const float*)d_in[5];
    const float* bl1   = (const float*)d_in[6];
    const float* Wr1   = (const float*)d_in[7];
    const float* br1   = (const float*)d_in[8];
    const float* att1  = (const float*)d_in[9];
    const float* bias1 = (const float*)d_in[10];
    const float* Wl2   = (const float*)d_in[11];
    const float* bl2   = (const float*)d_in[12];
    const float* Wr2   = (const float*)d_in[13];
    const float* br2   = (const float*)d_in[14];
    const float* att2  = (const float*)d_in[15];
    const float* bias2 = (const float*)d_in[16];
    const float* Wout  = (const float*)d_in[17];
    const float* b_out = (const float*)d_in[18];
    float* out = (float*)d_out;

    int N = in_sizes[0] / 128;  // 50000
    int E = in_sizes[1] / 2;    // 600000
    int Etot = E + N;
    int nbt = (N + 255) / 256;

    char* wsb = (char*)d_ws;
    size_t off = 0;
    auto alloc = [&](size_t bytes) { void* p = wsb + off; off += (bytes + 255) & ~(size_t)255; return p; };

    unsigned short* XL1   = (unsigned short*)alloc((size_t)N * 128 * 2);  // reused as XL2
    unsigned short* XR1   = (unsigned short*)alloc((size_t)N * 128 * 2);  // reused as XR2
    unsigned short* H1    = (unsigned short*)alloc((size_t)N * 128 * 2);
    unsigned short* Wcat1 = (unsigned short*)alloc(256 * 128 * 2);
    unsigned short* Wcat2 = (unsigned short*)alloc(64 * 128 * 2);
    float* bcat1   = (float*)alloc(256 * 4);
    float* bcat2   = (float*)alloc(64 * 4);
    float* pooledR = (float*)alloc(NREP * 32 * 4);
    int* rowstart  = (int*)alloc((size_t)(N + 1) * 4);
    int* deg       = (int*)alloc((size_t)N * 4);
    int* cursor    = (int*)alloc((size_t)N * 4);
    int* csr_src   = (int*)alloc((size_t)Etot * 4);
    int* partial   = (int*)alloc((size_t)nbt * 4);
    unsigned short* XL2 = XL1;
    unsigned short* XR2 = XR1;

    hipMemsetAsync(deg, 0, (size_t)N * 4, stream);

    // --- CSR build ---
    hist_kernel<<<(Etot + 255) / 256, 256, 0, stream>>>(ei, deg, E, Etot);
    blocksum_kernel<<<nbt, 256, 0, stream>>>(deg, partial, pooledR, N);
    scanfinal_kernel<<<nbt, 256, 0, stream>>>(deg, partial, rowstart, cursor, N, nbt, Etot);
    scatter_kernel<<<(Etot + 255) / 256, 256, 0, stream>>>(ei, cursor, csr_src, E, Etot);

    // --- weight prep ---
    fold1_kernel<<<288, 128, 0, stream>>>(Win, b_in, Wl1, bl1, Wr1, br1,
                                          Wl2, bl2, Wr2, br2, Wcat1, bcat1, Wcat2, bcat2);

    // --- conv1 (32-row blocks for occupancy) ---
    gemm_mfma<2, 4, 128, true><<<(N + 31) / 32, 256, 0, stream>>>(x, Wcat1, bcat1, XL1, XR1, N);
    node_conv1<<<(N + 7) / 8, 256, 0, stream>>>(XL1, XR1, rowstart, csr_src, att1, bias1, H1, N);

    // --- conv2 ---
    gemm_mfma<4, 1, 32, false><<<(N + 63) / 64, 256, 0, stream>>>(H1, Wcat2, bcat2, XL2, XR2, N);
    node_conv2<<<1024, 256, 0, stream>>>(XL2, XR2, rowstart, csr_src, att2, bias2, pooledR, N);

    // --- out ---
    out_kernel<<<1, 128, 0, stream>>>(pooledR, Wout, b_out, out, N);
}